// Round 2
// baseline (101.027 us; speedup 1.0000x reference)
//
#include <hip/hip_runtime.h>

#define FEAT 512
#define REL_DIM 64
#define N_DRUGS 2000
#define N_TARGETS 4000
#define N_TRI 131072

__device__ __forceinline__ float dot4(float4 a, float4 b) {
    return a.x * b.x + a.y * b.y + a.z * b.z + a.w * b.w;
}

__device__ __forceinline__ float waveReduce(float v) {
#pragma unroll
    for (int off = 32; off; off >>= 1) v += __shfl_xor(v, off, 64);
    return v;
}

// One wave (64 lanes) per entity row. Rows [0,2000) = drugs, [2000,6000) = targets,
// row 6000 = the 8+8 relation scalars.
__global__ __launch_bounds__(256) void precompute_kernel(
    const float* __restrict__ d_intra, const float* __restrict__ d_inter,
    const float* __restrict__ t_intra, const float* __restrict__ t_inter,
    const float* __restrict__ rel_emb_intra, const float* __restrict__ rel_emb_inter,
    const float* __restrict__ W_intra, const float* __restrict__ b_intra,
    const float* __restrict__ W_inter, const float* __restrict__ b_inter,
    float* __restrict__ preD, float* __restrict__ preT,
    float* __restrict__ rel1, float* __restrict__ rel2)
{
    const int wave = threadIdx.x >> 6;
    const int lane = threadIdx.x & 63;
    const int row  = blockIdx.x * 4 + wave;

    if (row < N_DRUGS + N_TARGETS) {
        const float* fA;  // intra features
        const float* fB;  // inter features
        float* outp;
        if (row < N_DRUGS) {
            fA = d_intra + (size_t)row * FEAT;
            fB = d_inter + (size_t)row * FEAT;
            outp = preD + row * 4;
        } else {
            const int t = row - N_DRUGS;
            fA = t_intra + (size_t)t * FEAT;
            fB = t_inter + (size_t)t * FEAT;
            outp = preT + t * 4;
        }
        // 512 floats = 128 float4; lane i handles float4 #i and #(i+64).
        const float4* a4 = (const float4*)fA;
        const float4* b4 = (const float4*)fB;
        const float4* w1 = (const float4*)W_intra;  // [0,128)=Wu [128,256)=Wv
        const float4* w2 = (const float4*)W_inter;

        const float4 aA0 = a4[lane],        aA1 = a4[lane + 64];
        const float4 bB0 = b4[lane],        bB1 = b4[lane + 64];
        const float4 wu10 = w1[lane],       wu11 = w1[lane + 64];
        const float4 wv10 = w1[lane + 128], wv11 = w1[lane + 192];
        const float4 wu20 = w2[lane],       wu21 = w2[lane + 64];
        const float4 wv20 = w2[lane + 128], wv21 = w2[lane + 192];

        float s_u1 = dot4(aA0, wu10) + dot4(aA1, wu11);
        float s_v1 = dot4(aA0, wv10) + dot4(aA1, wv11);
        float s_u2 = dot4(bB0, wu20) + dot4(bB1, wu21);
        float s_v2 = dot4(bB0, wv20) + dot4(bB1, wv21);

        s_u1 = waveReduce(s_u1);
        s_v1 = waveReduce(s_v1);
        s_u2 = waveReduce(s_u2);
        s_v2 = waveReduce(s_v2);

        if (lane == 0) {
            outp[0] = s_u1;  // u-slot, intra
            outp[1] = s_v1;  // v-slot, intra
            outp[2] = s_u2;  // u-slot, inter
            outp[3] = s_v2;  // v-slot, inter
        }
    } else if (row == N_DRUGS + N_TARGETS) {
        // Relation scalars: REL_DIM==64 == wave width, one reduce per rel.
        const float b1 = b_intra[0];
        const float b2 = b_inter[0];
        const float wr1 = W_intra[2 * FEAT + lane];
        const float wr2 = W_inter[2 * FEAT + lane];
#pragma unroll
        for (int r = 0; r < 8; ++r) {
            float p1 = rel_emb_intra[r * REL_DIM + lane] * wr1;
            float p2 = rel_emb_inter[r * REL_DIM + lane] * wr2;
            p1 = waveReduce(p1);
            p2 = waveReduce(p2);
            if (lane == 0) {
                rel1[r] = p1 + b1;
                rel2[r] = p2 + b2;
            }
        }
    }
}

__global__ __launch_bounds__(256) void triplet_kernel(
    const int* __restrict__ triplets,
    const int* __restrict__ did_sub, const int* __restrict__ tid_sub,
    const float* __restrict__ preD, const float* __restrict__ preT,
    const float* __restrict__ rel1, const float* __restrict__ rel2,
    float* __restrict__ out)
{
    const int i = blockIdx.x * blockDim.x + threadIdx.x;
    if (i >= N_TRI) return;

    const int u = triplets[3 * i + 0];
    const int v = triplets[3 * i + 1];
    const int r = triplets[3 * i + 2];

    // u_is_drug = (r % 2 == 0); v_is_drug = ((r / 2) % 2 == 0). r in [0,8).
    const bool ud = (r & 1) == 0;
    const bool vd = ((r >> 1) & 1) == 0;

    float cu1, cu2, cv1, cv2;
    if (ud) { const int d = did_sub[u]; cu1 = preD[d * 4 + 0]; cu2 = preD[d * 4 + 2]; }
    else    { const int t = tid_sub[u]; cu1 = preT[t * 4 + 0]; cu2 = preT[t * 4 + 2]; }
    if (vd) { const int d = did_sub[v]; cv1 = preD[d * 4 + 1]; cv2 = preD[d * 4 + 3]; }
    else    { const int t = tid_sub[v]; cv1 = preT[t * 4 + 1]; cv2 = preT[t * 4 + 3]; }

    const float s1 = cu1 + cv1 + rel1[r];
    const float s2 = cu2 + cv2 + rel2[r];
    out[i] = 0.6f * tanhf(s1) + 0.2f * tanhf(s2);
}

extern "C" void kernel_launch(void* const* d_in, const int* in_sizes, int n_in,
                              void* d_out, int out_size, void* d_ws, size_t ws_size,
                              hipStream_t stream) {
    const float* d_intra        = (const float*)d_in[0];
    const float* d_inter        = (const float*)d_in[1];
    const float* t_intra        = (const float*)d_in[2];
    const float* t_inter        = (const float*)d_in[3];
    const int*   did_sub        = (const int*)d_in[4];
    const int*   tid_sub        = (const int*)d_in[5];
    const int*   triplets       = (const int*)d_in[6];
    // d_in[7], d_in[8]: u_is_drug / v_is_drug — derived arithmetically from r.
    const float* rel_emb_intra  = (const float*)d_in[9];
    const float* rel_emb_inter  = (const float*)d_in[10];
    const float* W_intra        = (const float*)d_in[11];
    const float* b_intra        = (const float*)d_in[12];
    const float* W_inter        = (const float*)d_in[13];
    const float* b_inter        = (const float*)d_in[14];

    float* ws   = (float*)d_ws;
    float* preD = ws;                     // 2000*4 floats
    float* preT = ws + N_DRUGS * 4;       // 4000*4 floats
    float* rel1 = preT + N_TARGETS * 4;   // 8 floats
    float* rel2 = rel1 + 8;               // 8 floats

    const int rows = N_DRUGS + N_TARGETS + 1;            // +1 wave for rel scalars
    const int gridA = (rows + 3) / 4;                    // 4 waves/block
    precompute_kernel<<<gridA, 256, 0, stream>>>(
        d_intra, d_inter, t_intra, t_inter,
        rel_emb_intra, rel_emb_inter,
        W_intra, b_intra, W_inter, b_inter,
        preD, preT, rel1, rel2);

    const int gridB = (N_TRI + 255) / 256;
    triplet_kernel<<<gridB, 256, 0, stream>>>(
        triplets, did_sub, tid_sub, preD, preT, rel1, rel2, (float*)d_out);
}